// Round 4
// baseline (139.381 us; speedup 1.0000x reference)
//
#include <hip/hip_runtime.h>
#include <stdint.h>

#define REG_P   0.05f
#define LOG2E   1.4426950408889634f
#define LN2     0.6931471805599453f
#define NSPLIT  8

typedef __bf16 bf16x8 __attribute__((ext_vector_type(8)));
typedef float  floatx4 __attribute__((ext_vector_type(4)));

__device__ inline unsigned int pack_bf16x2(float a, float b) {
    unsigned int ua = __float_as_uint(a);
    unsigned int ub = __float_as_uint(b);
    ua = (ua + 0x7FFFu + ((ua >> 16) & 1u)) >> 16;
    ub = (ub + 0x7FFFu + ((ub >> 16) & 1u)) >> 16;
    return ua | (ub << 16);
}

// k1: pack fp32->bf16 + per-row squared norms. 256 thr = 16 rows x 16 chunks.
// S rows -> row-major Sb. T rows -> MFMA-fragment-shuffled Tbs:
//   tile t (64 cols), chunk c = (g*4+kk)*64 + quad*16 + l16 holds
//   T[64t + g*16 + l16][kk*32 + quad*8 .. +7]   (16B each)
__global__ void k1_pack(const float* __restrict__ src, const float* __restrict__ tgt,
                        unsigned short* __restrict__ Sb, unsigned short* __restrict__ Tbs,
                        float* __restrict__ sx2, float* __restrict__ ty2,
                        int N, int M) {
    int tid = threadIdx.x;
    int r16 = tid >> 4;
    int c8  = tid & 15;
    int row_id = blockIdx.x * 16 + r16;
    bool isS = row_id < N;
    int row = isS ? row_id : row_id - N;
    const float4* sp = (const float4*)((isS ? src : tgt) + (size_t)row * 128 + c8 * 8);
    float4 f0 = sp[0], f1 = sp[1];
    uint4 val;
    val.x = pack_bf16x2(f0.x, f0.y);
    val.y = pack_bf16x2(f0.z, f0.w);
    val.z = pack_bf16x2(f1.x, f1.y);
    val.w = pack_bf16x2(f1.z, f1.w);
    float sq = f0.x*f0.x + f0.y*f0.y + f0.z*f0.z + f0.w*f0.w
             + f1.x*f1.x + f1.y*f1.y + f1.z*f1.z + f1.w*f1.w;
    #pragma unroll
    for (int mask = 1; mask < 16; mask <<= 1) sq += __shfl_xor(sq, mask, 16);
    if (isS) {
        ((uint4*)(Sb + (size_t)row * 128 + c8 * 8))[0] = val;
        if (c8 == 0) sx2[row] = sq;
    } else {
        int t = row >> 6, jc = row & 63;
        int g = jc >> 4, l16 = jc & 15;
        int kk = c8 >> 2, quad = c8 & 3;
        size_t dst = (size_t)t * 8192 + (size_t)(((g * 4 + kk) * 64 + quad * 16 + l16) * 8);
        ((uint4*)(Tbs + dst))[0] = val;
        if (c8 == 0) ty2[row] = sq;
    }
}

// k1b: SINGLE block. Writes (not accumulates) scal[0]=sum ty2, scal[1]=sum sx2,
// scal[2]=sum psi; zero-inits scal[3] and the k4 completion counter. No memset needed.
__global__ void k1b_sums(const float* __restrict__ sx2, const float* __restrict__ ty2,
                         const float* __restrict__ psi, float* __restrict__ scal,
                         int N, int M) {
    __shared__ float red[3][4];
    int tid = threadIdx.x;
    float s_sx = 0.f, s_ty = 0.f, s_ps = 0.f;
    for (int i = tid; i < N; i += 256) s_sx += sx2[i];
    for (int j = tid; j < M; j += 256) { s_ty += ty2[j]; s_ps += psi[j]; }
    #pragma unroll
    for (int off = 32; off > 0; off >>= 1) {
        s_sx += __shfl_xor(s_sx, off, 64);
        s_ty += __shfl_xor(s_ty, off, 64);
        s_ps += __shfl_xor(s_ps, off, 64);
    }
    int wv = tid >> 6, lane = tid & 63;
    if (lane == 0) { red[0][wv] = s_sx; red[1][wv] = s_ty; red[2][wv] = s_ps; }
    __syncthreads();
    if (tid == 0) {
        scal[1] = red[0][0] + red[0][1] + red[0][2] + red[0][3];
        scal[0] = red[1][0] + red[1][1] + red[1][2] + red[1][3];
        scal[2] = red[2][0] + red[2][1] + red[2][2] + red[2][3];
        scal[3] = 0.0f;
        ((unsigned int*)scal)[4] = 0u;   // k4 completion counter
    }
}

__device__ __forceinline__ void k3_compute(const bf16x8 (&bc)[4],
                                           const bf16x8 (&afrag)[2][4],
                                           float (&ls)[2][4], float a2, float bv) {
    #pragma unroll
    for (int rt = 0; rt < 2; ++rt) {
        floatx4 acc = (floatx4){0.f, 0.f, 0.f, 0.f};
        #pragma unroll
        for (int kk = 0; kk < 4; ++kk)
            acc = __builtin_amdgcn_mfma_f32_16x16x32_bf16(afrag[rt][kk], bc[kk], acc, 0, 0, 0);
        #pragma unroll
        for (int r = 0; r < 4; ++r)
            ls[rt][r] += __builtin_amdgcn_exp2f(fmaf(a2, acc[r], bv));
    }
}

// k3: l_i = sum_j exp2(b2_j + a2*dot_ij), no max shift (exponent in [-90,+32],
// fp32-safe; sub-2^-126 contributions flushed by v_exp_f32 are negligible vs
// row sums >= ~2^-50). Block = 128 rows x one M-split (1024 cols). 4 waves,
// each owns 32 rows x all 64 cols of each tile. B fragments loaded GLOBAL->VGPR
// directly from fragment-ordered Tbs (16B/lane contiguous), register
// double-buffered: ZERO barriers in the K loop, no LDS staging.
// split = blockIdx&7 -> one split per XCD (round-robin dispatch): 2MB hot
// B-region per XCD L2.
__global__ __launch_bounds__(256) void k3_main(
    const unsigned short* __restrict__ Sb, const unsigned short* __restrict__ Tbs,
    const float* __restrict__ psi, const float* __restrict__ ty2,
    const float* __restrict__ scal, float* __restrict__ lpart, int N, int M) {
    __shared__ float sb2a[1024];
    const int tid  = threadIdx.x;
    const int lane = tid & 63;
    const int wv   = tid >> 6;
    const int quad = lane >> 4, l16 = lane & 15;
    const int b = blockIdx.x;
    const int split = b & 7;
    const int i0 = (b >> 3) * 128;
    const int mspan = M / NSPLIT;            // 1024
    const int jstart = split * mspan;
    const int NU = (mspan / 64) * 4;         // 64 chunk-groups of 16 cols

    float scale = scal[0] / (float)M;
    float c1 = 1.0f / (REG_P * scale);
    float a2 = 2.0f * LOG2E / (REG_P * scale);

    // b2 slice for this split, computed in-block (k2 fused away)
    for (int idx = tid; idx < mspan; idx += 256) {
        int j = jstart + idx;
        sb2a[idx] = (psi[j] * (1.0f / REG_P) - ty2[j] * c1) * LOG2E;
    }
    __syncthreads();   // the only barrier

    // A fragments, register-resident: A[m=l16][k=quad*8+j], rows i0+wv*32+rt*16+l16
    bf16x8 afrag[2][4];
    #pragma unroll
    for (int rt = 0; rt < 2; ++rt)
        #pragma unroll
        for (int kk = 0; kk < 4; ++kk)
            afrag[rt][kk] = *reinterpret_cast<const bf16x8*>(
                Sb + (size_t)(i0 + wv * 32 + rt * 16 + l16) * 128 + kk * 32 + quad * 8);

    float ls[2][4];
    #pragma unroll
    for (int rt = 0; rt < 2; ++rt)
        #pragma unroll
        for (int r = 0; r < 4; ++r) ls[rt][r] = 0.0f;

    // per-lane B pointer: tile = jstart/64, chunk-group g strides 2048 shorts
    const unsigned short* gp = Tbs + (size_t)(jstart >> 6) * 8192 + (size_t)lane * 8;

    bf16x8 bc[4], bn[4];
    #pragma unroll
    for (int kk = 0; kk < 4; ++kk)
        bc[kk] = *reinterpret_cast<const bf16x8*>(gp + kk * 512);

    #pragma unroll 4
    for (int u = 0; u < NU - 1; ++u) {
        gp += 2048;
        #pragma unroll
        for (int kk = 0; kk < 4; ++kk)
            bn[kk] = *reinterpret_cast<const bf16x8*>(gp + kk * 512);
        float bv = sb2a[(u << 4) + l16];
        k3_compute(bc, afrag, ls, a2, bv);
        #pragma unroll
        for (int kk = 0; kk < 4; ++kk) bc[kk] = bn[kk];
    }
    {
        float bv = sb2a[((NU - 1) << 4) + l16];
        k3_compute(bc, afrag, ls, a2, bv);
    }

    // sum over the 16 lanes (l16) sharing each row
    #pragma unroll
    for (int rt = 0; rt < 2; ++rt)
        #pragma unroll
        for (int r = 0; r < 4; ++r) {
            float v = ls[rt][r];
            #pragma unroll
            for (int mask = 1; mask < 16; mask <<= 1) v += __shfl_xor(v, mask, 64);
            if (l16 == 0) {
                int rowg = i0 + wv * 32 + rt * 16 + quad * 4 + r;
                lpart[(size_t)rowg * NSPLIT + split] = v;
            }
        }
}

// k4: L2_i = log2(sum of 8 partials); block reduce; last-done block (device-scope
// counter) computes the final scalar (k5 fused away).
__global__ void k4_reduce(const float* __restrict__ lpart, float* __restrict__ scal,
                          float* __restrict__ out, int N, int M) {
    __shared__ float red[4];
    int i = blockIdx.x * blockDim.x + threadIdx.x;
    const float4* lp = (const float4*)(lpart + (size_t)i * NSPLIT);
    float4 p0 = lp[0], p1 = lp[1];
    float s = (p0.x + p0.y + p0.z + p0.w) + (p1.x + p1.y + p1.z + p1.w);
    float L2 = __builtin_amdgcn_logf(s);   // v_log_f32 = log2
    #pragma unroll
    for (int off = 32; off > 0; off >>= 1) L2 += __shfl_xor(L2, off, 64);
    int wv = threadIdx.x >> 6, lane = threadIdx.x & 63;
    if (lane == 0) red[wv] = L2;
    __syncthreads();
    if (threadIdx.x == 0) {
        atomicAdd(&scal[3], red[0] + red[1] + red[2] + red[3]);
        __threadfence();
        unsigned int old = atomicAdd((unsigned int*)scal + 4, 1u);
        if (old == gridDim.x - 1) {
            __threadfence();
            float s3 = atomicAdd(&scal[3], 0.0f);   // coherent read
            float scale = scal[0] / (float)M;
            out[0] = (scal[1] / (float)N) / scale
                   - REG_P * LN2 * (s3 / (float)N)
                   + scal[2] / (float)M
                   + REG_P * logf((float)M);
        }
    }
}

extern "C" void kernel_launch(void* const* d_in, const int* in_sizes, int n_in,
                              void* d_out, int out_size, void* d_ws, size_t ws_size,
                              hipStream_t stream) {
    const float* src = (const float*)d_in[0];
    const float* tgt = (const float*)d_in[1];
    const float* psi = (const float*)d_in[2];
    const int D = 128;
    const int N = in_sizes[0] / D;   // 16384
    const int M = in_sizes[1] / D;   // 8192

    char* ws = (char*)d_ws;
    float* scal  = (float*)ws;                                      // 8 slots
    float* sx2   = (float*)(ws + 256);
    float* ty2   = (float*)(ws + 256 + (size_t)N * 4);
    float* lpart = (float*)(ws + 256 + (size_t)N * 4 + (size_t)M * 4);
    size_t off = 256 + (size_t)N * 4 + (size_t)M * 4 + (size_t)N * NSPLIT * 4;
    off = (off + 255) & ~(size_t)255;
    unsigned short* Sb  = (unsigned short*)(ws + off);
    unsigned short* Tbs = Sb + (size_t)N * 128;

    k1_pack<<<(N + M) / 16, 256, 0, stream>>>(src, tgt, Sb, Tbs, sx2, ty2, N, M);
    k1b_sums<<<1, 256, 0, stream>>>(sx2, ty2, psi, scal, N, M);
    k3_main<<<(N / 128) * NSPLIT, 256, 0, stream>>>(Sb, Tbs, psi, ty2, scal, lpart, N, M);
    k4_reduce<<<N / 256, 256, 0, stream>>>(lpart, scal, (float*)d_out, N, M);
}

// Round 6
// 113.057 us; speedup vs baseline: 1.2328x; 1.2328x over previous
//
#include <hip/hip_runtime.h>
#include <stdint.h>

#define REG_P   0.05f
#define LOG2E   1.4426950408889634f
#define LN2     0.6931471805599453f
#define NSPLIT  8

typedef __bf16 bf16x8 __attribute__((ext_vector_type(8)));
typedef float  floatx4 __attribute__((ext_vector_type(4)));

// async global->LDS, 16B per lane: lane i writes ldsbase + i*16.
#define GLOAD_LDS16(gp, lp)                                                     \
    __builtin_amdgcn_global_load_lds(                                           \
        (const __attribute__((address_space(1))) unsigned int*)(uintptr_t)(gp), \
        (__attribute__((address_space(3))) unsigned int*)(uintptr_t)(lp),       \
        16, 0, 0)

__device__ inline unsigned int pack_bf16x2(float a, float b) {
    unsigned int ua = __float_as_uint(a);
    unsigned int ub = __float_as_uint(b);
    ua = (ua + 0x7FFFu + ((ua >> 16) & 1u)) >> 16;
    ub = (ub + 0x7FFFu + ((ub >> 16) & 1u)) >> 16;
    return ua | (ub << 16);
}

// sum of p[0..31], wave-parallel: lane&31 loads, butterfly masks 1..16 stay
// within each 32-lane half; each half sums the 32 distinct values exactly.
// EVERY lane returns the EXACT sum (no double-count — do NOT scale).
__device__ inline float sum32(const float* __restrict__ p, int lane) {
    float v = p[lane & 31];
    #pragma unroll
    for (int mask = 1; mask < 32; mask <<= 1) v += __shfl_xor(v, mask, 64);
    return v;
}

// k1: pack fp32->bf16 + per-row squared norms. 256 thr = 16 rows x 16 chunks.
// S rows -> row-major Sb. T rows -> MFMA-fragment-shuffled Tbs:
//   tile t (64 cols), chunk c = (g*4+kk)*64 + quad*16 + l16 holds
//   T[64t + g*16 + l16][kk*32 + quad*8 .. +7]   (16B each)
__global__ void k1_pack(const float* __restrict__ src, const float* __restrict__ tgt,
                        unsigned short* __restrict__ Sb, unsigned short* __restrict__ Tbs,
                        float* __restrict__ sx2, float* __restrict__ ty2,
                        int N, int M) {
    int tid = threadIdx.x;
    int r16 = tid >> 4;
    int c8  = tid & 15;
    int row_id = blockIdx.x * 16 + r16;
    bool isS = row_id < N;
    int row = isS ? row_id : row_id - N;
    const float4* sp = (const float4*)((isS ? src : tgt) + (size_t)row * 128 + c8 * 8);
    float4 f0 = sp[0], f1 = sp[1];
    uint4 val;
    val.x = pack_bf16x2(f0.x, f0.y);
    val.y = pack_bf16x2(f0.z, f0.w);
    val.z = pack_bf16x2(f1.x, f1.y);
    val.w = pack_bf16x2(f1.z, f1.w);
    float sq = f0.x*f0.x + f0.y*f0.y + f0.z*f0.z + f0.w*f0.w
             + f1.x*f1.x + f1.y*f1.y + f1.z*f1.z + f1.w*f1.w;
    #pragma unroll
    for (int mask = 1; mask < 16; mask <<= 1) sq += __shfl_xor(sq, mask, 16);
    if (isS) {
        ((uint4*)(Sb + (size_t)row * 128 + c8 * 8))[0] = val;
        if (c8 == 0) sx2[row] = sq;
    } else {
        int t = row >> 6, jc = row & 63;
        int g = jc >> 4, l16 = jc & 15;
        int kk = c8 >> 2, quad = c8 & 3;
        size_t dst = (size_t)t * 8192 + (size_t)(((g * 4 + kk) * 64 + quad * 16 + l16) * 8);
        ((uint4*)(Tbs + dst))[0] = val;
        if (c8 == 0) ty2[row] = sq;
    }
}

// k1b: 32 blocks. NO atomics: per-block partials to scalpart[3][32]
// (0: sum ty2, 1: sum sx2, 2: sum psi). Block 0 zero-inits d_out (k4 accumulates
// into it atomically; k1b precedes k4 in stream order).
__global__ void k1b_sums(const float* __restrict__ sx2, const float* __restrict__ ty2,
                         const float* __restrict__ psi, float* __restrict__ scalpart,
                         float* __restrict__ out, int N, int M) {
    __shared__ float red[3][4];
    int tid = threadIdx.x;
    int gid = blockIdx.x * 256 + tid;
    float s_sx = 0.f, s_ty = 0.f, s_ps = 0.f;
    for (int i = gid; i < N; i += 32 * 256) s_sx += sx2[i];
    for (int j = gid; j < M; j += 32 * 256) { s_ty += ty2[j]; s_ps += psi[j]; }
    #pragma unroll
    for (int off = 32; off > 0; off >>= 1) {
        s_sx += __shfl_xor(s_sx, off, 64);
        s_ty += __shfl_xor(s_ty, off, 64);
        s_ps += __shfl_xor(s_ps, off, 64);
    }
    int wv = tid >> 6, lane = tid & 63;
    if (lane == 0) { red[0][wv] = s_ty; red[1][wv] = s_sx; red[2][wv] = s_ps; }
    __syncthreads();
    if (tid == 0) {
        scalpart[blockIdx.x]      = red[0][0] + red[0][1] + red[0][2] + red[0][3];
        scalpart[32 + blockIdx.x] = red[1][0] + red[1][1] + red[1][2] + red[1][3];
        scalpart[64 + blockIdx.x] = red[2][0] + red[2][1] + red[2][2] + red[2][3];
        if (blockIdx.x == 0) out[0] = 0.0f;
    }
}

// k3: l_i = sum_j exp2(b2_j + a2*dot_ij), no max shift (exponent in [-90,+32],
// fp32-safe). Block = 128 rows x one M-split (1024 cols = 16 tiles of 64).
// 4 waves, each 32 rows x all 64 cols. B staged ONCE per block into LDS
// (global_load_lds 16B, fragment order -> ds_read_b128 conflict-free),
// single-barrier double-buffer: prefetch tile t+1 while computing tile t.
__global__ __launch_bounds__(256) void k3_main(
    const unsigned short* __restrict__ Sb, const unsigned short* __restrict__ Tbs,
    const float* __restrict__ psi, const float* __restrict__ ty2,
    const float* __restrict__ scalpart, float* __restrict__ lpart, int N, int M) {
    __shared__ __align__(16) unsigned short sT[2][8192];   // 2 x 16 KB tiles
    __shared__ float sb2a[1024];
    const int tid  = threadIdx.x;
    const int lane = tid & 63;
    const int wv   = tid >> 6;
    const int quad = lane >> 4, l16 = lane & 15;
    const int b = blockIdx.x;
    const int split = b & 7;                  // one split per XCD (round-robin)
    const int i0 = (b >> 3) * 128;
    const int mspan = M / NSPLIT;             // 1024
    const int jstart = split * mspan;
    const int ntile = mspan / 64;             // 16

    float ty2sum = sum32(scalpart, lane);     // exact sum (no scaling!)
    float scale = ty2sum / (float)M;
    float c1 = 1.0f / (REG_P * scale);
    float a2 = 2.0f * LOG2E / (REG_P * scale);

    // b2 slice for this split (k2 fused)
    for (int idx = tid; idx < mspan; idx += 256) {
        int j = jstart + idx;
        sb2a[idx] = (psi[j] * (1.0f / REG_P) - ty2[j] * c1) * LOG2E;
    }

    // A fragments, register-resident: A[m=l16][k=quad*8+j], rows i0+wv*32+rt*16+l16
    bf16x8 afrag[2][4];
    #pragma unroll
    for (int rt = 0; rt < 2; ++rt)
        #pragma unroll
        for (int kk = 0; kk < 4; ++kk)
            afrag[rt][kk] = *reinterpret_cast<const bf16x8*>(
                Sb + (size_t)(i0 + wv * 32 + rt * 16 + l16) * 128 + kk * 32 + quad * 8);

    float ls[2][4];
    #pragma unroll
    for (int rt = 0; rt < 2; ++rt)
        #pragma unroll
        for (int r = 0; r < 4; ++r) ls[rt][r] = 0.0f;

    // staging: each wave stages 4 KB = 4 x (64 lanes x 16B); group (4*wv+c)
    const unsigned short* gp = Tbs + (size_t)(jstart >> 6) * 8192
                             + (size_t)(4 * wv) * 512 + (size_t)lane * 8;
    #pragma unroll
    for (int c = 0; c < 4; ++c)
        GLOAD_LDS16(gp + c * 512, &sT[0][(4 * wv + c) * 512]);
    __syncthreads();

    for (int tt = 0; tt < ntile; ++tt) {
        const int p = tt & 1;
        if (tt + 1 < ntile) {                 // prefetch next tile, no wait
            const unsigned short* gq = gp + (size_t)(tt + 1) * 8192;
            #pragma unroll
            for (int c = 0; c < 4; ++c)
                GLOAD_LDS16(gq + c * 512, &sT[p ^ 1][(4 * wv + c) * 512]);
        }
        #pragma unroll
        for (int g = 0; g < 4; ++g) {
            bf16x8 bfrag[4];
            #pragma unroll
            for (int kk = 0; kk < 4; ++kk)
                bfrag[kk] = *reinterpret_cast<const bf16x8*>(
                    &sT[p][((g * 4 + kk) * 64 + lane) * 8]);
            float bv = sb2a[tt * 64 + g * 16 + l16];
            #pragma unroll
            for (int rt = 0; rt < 2; ++rt) {
                floatx4 acc = (floatx4){0.f, 0.f, 0.f, 0.f};
                #pragma unroll
                for (int kk = 0; kk < 4; ++kk)
                    acc = __builtin_amdgcn_mfma_f32_16x16x32_bf16(
                        afrag[rt][kk], bfrag[kk], acc, 0, 0, 0);
                #pragma unroll
                for (int r = 0; r < 4; ++r)
                    ls[rt][r] += __builtin_amdgcn_exp2f(fmaf(a2, acc[r], bv));
            }
        }
        __syncthreads();   // one barrier per tile; prefetch latency covered by compute
    }

    // sum over the 16 lanes (l16) sharing each row
    #pragma unroll
    for (int rt = 0; rt < 2; ++rt)
        #pragma unroll
        for (int r = 0; r < 4; ++r) {
            float v = ls[rt][r];
            #pragma unroll
            for (int mask = 1; mask < 16; mask <<= 1) v += __shfl_xor(v, mask, 64);
            if (l16 == 0) {
                int rowg = i0 + wv * 32 + rt * 16 + quad * 4 + r;
                lpart[(size_t)rowg * NSPLIT + split] = v;
            }
        }
}

// k4: one row per thread; L2_i = log2(sum of 8 partials); block partial ->
// atomicAdd of the scaled term into d_out. Block 0 adds the constant terms.
__global__ void k4_reduce(const float* __restrict__ lpart,
                          const float* __restrict__ scalpart,
                          float* __restrict__ out, int N, int M) {
    __shared__ float red[4];
    int i = blockIdx.x * 256 + threadIdx.x;
    const float4* lp = (const float4*)(lpart + (size_t)i * NSPLIT);
    float4 p0 = lp[0], p1 = lp[1];
    float s = (p0.x + p0.y + p0.z + p0.w) + (p1.x + p1.y + p1.z + p1.w);
    float L2 = __builtin_amdgcn_logf(s);     // v_log_f32 = log2
    #pragma unroll
    for (int off = 32; off > 0; off >>= 1) L2 += __shfl_xor(L2, off, 64);
    int wv = threadIdx.x >> 6, lane = threadIdx.x & 63;
    if (lane == 0) red[wv] = L2;
    __syncthreads();
    if (threadIdx.x == 0) {
        float blocksum = red[0] + red[1] + red[2] + red[3];
        atomicAdd(out, -REG_P * LN2 / (float)N * blocksum);
    }
    if (blockIdx.x == 0) {
        float ty2s = sum32(scalpart, lane);        // exact sums (no scaling!)
        float sx2s = sum32(scalpart + 32, lane);
        float psis = sum32(scalpart + 64, lane);
        if (threadIdx.x == 0) {
            float scale = ty2s / (float)M;
            atomicAdd(out, (sx2s / (float)N) / scale
                         + psis / (float)M
                         + REG_P * logf((float)M));
        }
    }
}

extern "C" void kernel_launch(void* const* d_in, const int* in_sizes, int n_in,
                              void* d_out, int out_size, void* d_ws, size_t ws_size,
                              hipStream_t stream) {
    const float* src = (const float*)d_in[0];
    const float* tgt = (const float*)d_in[1];
    const float* psi = (const float*)d_in[2];
    const int D = 128;
    const int N = in_sizes[0] / D;   // 16384
    const int M = in_sizes[1] / D;   // 8192

    char* ws = (char*)d_ws;
    float* scalpart = (float*)ws;                                   // 3 x 32 floats
    float* sx2   = (float*)(ws + 512);
    float* ty2   = (float*)(ws + 512 + (size_t)N * 4);
    float* lpart = (float*)(ws + 512 + (size_t)N * 4 + (size_t)M * 4);
    size_t off = 512 + (size_t)N * 4 + (size_t)M * 4 + (size_t)N * NSPLIT * 4;
    off = (off + 255) & ~(size_t)255;
    unsigned short* Sb  = (unsigned short*)(ws + off);
    unsigned short* Tbs = Sb + (size_t)N * 128;

    k1_pack<<<(N + M) / 16, 256, 0, stream>>>(src, tgt, Sb, Tbs, sx2, ty2, N, M);
    k1b_sums<<<32, 256, 0, stream>>>(sx2, ty2, psi, scalpart, (float*)d_out, N, M);
    k3_main<<<(N / 128) * NSPLIT, 256, 0, stream>>>(Sb, Tbs, psi, ty2, scalpart, lpart, N, M);
    k4_reduce<<<N / 256, 256, 0, stream>>>(lpart, scalpart, (float*)d_out, N, M);
}

// Round 7
// 112.834 us; speedup vs baseline: 1.2353x; 1.0020x over previous
//
#include <hip/hip_runtime.h>
#include <stdint.h>

#define REG_P   0.05f
#define LOG2E   1.4426950408889634f
#define LN2     0.6931471805599453f
#define NSPLIT  8

typedef __bf16 bf16x8 __attribute__((ext_vector_type(8)));
typedef float  floatx4 __attribute__((ext_vector_type(4)));

// async global->LDS, 16B per lane: lane i writes ldsbase + i*16.
#define GLOAD_LDS16(gp, lp)                                                     \
    __builtin_amdgcn_global_load_lds(                                           \
        (const __attribute__((address_space(1))) unsigned int*)(uintptr_t)(gp), \
        (__attribute__((address_space(3))) unsigned int*)(uintptr_t)(lp),       \
        16, 0, 0)

__device__ inline unsigned int pack_bf16x2(float a, float b) {
    unsigned int ua = __float_as_uint(a);
    unsigned int ub = __float_as_uint(b);
    ua = (ua + 0x7FFFu + ((ua >> 16) & 1u)) >> 16;
    ub = (ub + 0x7FFFu + ((ub >> 16) & 1u)) >> 16;
    return ua | (ub << 16);
}

// scale a bf16x8 fragment by s (f32 math, round-to-nearest repack)
__device__ inline bf16x8 scale_frag(bf16x8 v, float s) {
    bf16x8 r;
    #pragma unroll
    for (int i = 0; i < 8; i += 2) {
        float a = (float)v[i] * s;
        float b = (float)v[i + 1] * s;
        union { unsigned int u; __bf16 h[2]; } cvt;
        cvt.u = pack_bf16x2(a, b);
        r[i] = cvt.h[0]; r[i + 1] = cvt.h[1];
    }
    return r;
}

// sum of p[0..31]: butterfly masks 1..16 stay in each 32-lane half; every lane
// returns the exact 32-element sum (no scaling!).
__device__ inline float sum32(const float* __restrict__ p, int lane) {
    float v = p[lane & 31];
    #pragma unroll
    for (int mask = 1; mask < 32; mask <<= 1) v += __shfl_xor(v, mask, 64);
    return v;
}

// k1: pack fp32->bf16 + per-row squared norms. 256 thr = 16 rows x 16 chunks.
// S rows -> row-major Sb. T rows -> MFMA-fragment-shuffled Tbs:
//   tile t (64 cols), chunk c = (g*4+kk)*64 + quad*16 + l16 holds
//   T[64t + g*16 + l16][kk*32 + quad*8 .. +7]   (16B each)
__global__ void k1_pack(const float* __restrict__ src, const float* __restrict__ tgt,
                        unsigned short* __restrict__ Sb, unsigned short* __restrict__ Tbs,
                        float* __restrict__ sx2, float* __restrict__ ty2,
                        int N, int M) {
    int tid = threadIdx.x;
    int r16 = tid >> 4;
    int c8  = tid & 15;
    int row_id = blockIdx.x * 16 + r16;
    bool isS = row_id < N;
    int row = isS ? row_id : row_id - N;
    const float4* sp = (const float4*)((isS ? src : tgt) + (size_t)row * 128 + c8 * 8);
    float4 f0 = sp[0], f1 = sp[1];
    uint4 val;
    val.x = pack_bf16x2(f0.x, f0.y);
    val.y = pack_bf16x2(f0.z, f0.w);
    val.z = pack_bf16x2(f1.x, f1.y);
    val.w = pack_bf16x2(f1.z, f1.w);
    float sq = f0.x*f0.x + f0.y*f0.y + f0.z*f0.z + f0.w*f0.w
             + f1.x*f1.x + f1.y*f1.y + f1.z*f1.z + f1.w*f1.w;
    #pragma unroll
    for (int mask = 1; mask < 16; mask <<= 1) sq += __shfl_xor(sq, mask, 16);
    if (isS) {
        ((uint4*)(Sb + (size_t)row * 128 + c8 * 8))[0] = val;
        if (c8 == 0) sx2[row] = sq;
    } else {
        int t = row >> 6, jc = row & 63;
        int g = jc >> 4, l16 = jc & 15;
        int kk = c8 >> 2, quad = c8 & 3;
        size_t dst = (size_t)t * 8192 + (size_t)(((g * 4 + kk) * 64 + quad * 16 + l16) * 8);
        ((uint4*)(Tbs + dst))[0] = val;
        if (c8 == 0) ty2[row] = sq;
    }
}

// k1b: 32 blocks. Per-block partials to scalpart[3][32]
// (0: sum ty2, 1: sum sx2, 2: sum psi). Block 0 zero-inits d_out.
// Kernel-boundary ordering makes these visible to k3/k4 — no atomics needed.
__global__ void k1b_sums(const float* __restrict__ sx2, const float* __restrict__ ty2,
                         const float* __restrict__ psi, float* __restrict__ scalpart,
                         float* __restrict__ out, int N, int M) {
    __shared__ float red[3][4];
    int tid = threadIdx.x;
    int gid = blockIdx.x * 256 + tid;
    float s_sx = 0.f, s_ty = 0.f, s_ps = 0.f;
    for (int i = gid; i < N; i += 32 * 256) s_sx += sx2[i];
    for (int j = gid; j < M; j += 32 * 256) { s_ty += ty2[j]; s_ps += psi[j]; }
    #pragma unroll
    for (int off = 32; off > 0; off >>= 1) {
        s_sx += __shfl_xor(s_sx, off, 64);
        s_ty += __shfl_xor(s_ty, off, 64);
        s_ps += __shfl_xor(s_ps, off, 64);
    }
    int wv = tid >> 6, lane = tid & 63;
    if (lane == 0) { red[0][wv] = s_ty; red[1][wv] = s_sx; red[2][wv] = s_ps; }
    __syncthreads();
    if (tid == 0) {
        scalpart[blockIdx.x]      = red[0][0] + red[0][1] + red[0][2] + red[0][3];
        scalpart[32 + blockIdx.x] = red[1][0] + red[1][1] + red[1][2] + red[1][3];
        scalpart[64 + blockIdx.x] = red[2][0] + red[2][1] + red[2][2] + red[2][3];
        if (blockIdx.x == 0) out[0] = 0.0f;
    }
}

// k3: l_i = sum_j exp2(b2_j + a2*dot_ij).  a2 folded into the bf16 A fragments
// (scaled once, register-resident); b2_j folded into the MFMA C-init (C/D col =
// l16 -> acc={bv} broadcast is exact). Epilogue = exp2 + add only.
// No max shift: exponent in [-90,+32], fp32-safe; row sums >= ~2^-50.
// Block = 2 waves x 64 rows = 128 rows, one M-split (1024 cols = 16 tiles).
// Each wave covers all 64 cols -> each 16KB B tile read only 2x from LDS.
// B staged via global_load_lds (fragment order -> ds_read_b128 conflict-free),
// single-barrier double-buffer.
__global__ __launch_bounds__(128) void k3_main(
    const unsigned short* __restrict__ Sb, const unsigned short* __restrict__ Tbs,
    const float* __restrict__ psi, const float* __restrict__ ty2,
    const float* __restrict__ scalpart, float* __restrict__ lpart, int N, int M) {
    __shared__ __align__(16) unsigned short sT[2][8192];   // 2 x 16 KB tiles
    __shared__ float sb2a[1024];
    const int tid  = threadIdx.x;
    const int lane = tid & 63;
    const int wv   = tid >> 6;                // 0..1
    const int quad = lane >> 4, l16 = lane & 15;
    const int b = blockIdx.x;
    const int split = b & 7;                  // one split per XCD (round-robin)
    const int i0 = (b >> 3) * 128;
    const int mspan = M / NSPLIT;             // 1024
    const int jstart = split * mspan;
    const int ntile = mspan / 64;             // 16

    float ty2sum = sum32(scalpart, lane);
    float scale = ty2sum / (float)M;
    float c1 = 1.0f / (REG_P * scale);
    float a2 = 2.0f * LOG2E / (REG_P * scale);

    // b2 slice for this split (k2 fused)
    for (int idx = tid; idx < mspan; idx += 128) {
        int j = jstart + idx;
        sb2a[idx] = (psi[j] * (1.0f / REG_P) - ty2[j] * c1) * LOG2E;
    }

    // A fragments x a2, register-resident: rows i0 + wv*64 + rt*16 + l16
    bf16x8 afrag[4][4];
    #pragma unroll
    for (int rt = 0; rt < 4; ++rt)
        #pragma unroll
        for (int kk = 0; kk < 4; ++kk)
            afrag[rt][kk] = scale_frag(*reinterpret_cast<const bf16x8*>(
                Sb + (size_t)(i0 + wv * 64 + rt * 16 + l16) * 128 + kk * 32 + quad * 8), a2);

    float ls[4][4];
    #pragma unroll
    for (int rt = 0; rt < 4; ++rt)
        #pragma unroll
        for (int r = 0; r < 4; ++r) ls[rt][r] = 0.0f;

    // staging: each of 2 waves stages 8 KB = 8 x (64 lanes x 16B)
    const unsigned short* gp = Tbs + (size_t)(jstart >> 6) * 8192
                             + (size_t)(8 * wv) * 512 + (size_t)lane * 8;
    #pragma unroll
    for (int c = 0; c < 8; ++c)
        GLOAD_LDS16(gp + c * 512, &sT[0][(8 * wv + c) * 512]);
    __syncthreads();

    for (int tt = 0; tt < ntile; ++tt) {
        const int p = tt & 1;
        if (tt + 1 < ntile) {                 // prefetch next tile, no wait
            const unsigned short* gq = gp + (size_t)(tt + 1) * 8192;
            #pragma unroll
            for (int c = 0; c < 8; ++c)
                GLOAD_LDS16(gq + c * 512, &sT[p ^ 1][(8 * wv + c) * 512]);
        }
        #pragma unroll
        for (int g = 0; g < 4; ++g) {
            bf16x8 bfrag[4];
            #pragma unroll
            for (int kk = 0; kk < 4; ++kk)
                bfrag[kk] = *reinterpret_cast<const bf16x8*>(
                    &sT[p][((g * 4 + kk) * 64 + lane) * 8]);
            float bv = sb2a[tt * 64 + g * 16 + l16];
            #pragma unroll
            for (int rt = 0; rt < 4; ++rt) {
                floatx4 acc = (floatx4){bv, bv, bv, bv};   // b2 as C-init
                #pragma unroll
                for (int kk = 0; kk < 4; ++kk)
                    acc = __builtin_amdgcn_mfma_f32_16x16x32_bf16(
                        afrag[rt][kk], bfrag[kk], acc, 0, 0, 0);
                #pragma unroll
                for (int r = 0; r < 4; ++r)
                    ls[rt][r] += __builtin_amdgcn_exp2f(acc[r]);
            }
        }
        __syncthreads();   // one barrier per tile; prefetch covered by compute
    }

    // sum over the 16 lanes (l16) sharing each row
    #pragma unroll
    for (int rt = 0; rt < 4; ++rt)
        #pragma unroll
        for (int r = 0; r < 4; ++r) {
            float v = ls[rt][r];
            #pragma unroll
            for (int mask = 1; mask < 16; mask <<= 1) v += __shfl_xor(v, mask, 64);
            if (l16 == 0) {
                int rowg = i0 + wv * 64 + rt * 16 + quad * 4 + r;
                lpart[(size_t)rowg * NSPLIT + split] = v;
            }
        }
}

// k4: one row per thread; L2_i = log2(sum of 8 partials); block partial ->
// atomicAdd of the scaled term into d_out. Block 0 adds the constant terms.
__global__ void k4_reduce(const float* __restrict__ lpart,
                          const float* __restrict__ scalpart,
                          float* __restrict__ out, int N, int M) {
    __shared__ float red[4];
    int i = blockIdx.x * 256 + threadIdx.x;
    const float4* lp = (const float4*)(lpart + (size_t)i * NSPLIT);
    float4 p0 = lp[0], p1 = lp[1];
    float s = (p0.x + p0.y + p0.z + p0.w) + (p1.x + p1.y + p1.z + p1.w);
    float L2 = __builtin_amdgcn_logf(s);     // v_log_f32 = log2
    #pragma unroll
    for (int off = 32; off > 0; off >>= 1) L2 += __shfl_xor(L2, off, 64);
    int wv = threadIdx.x >> 6, lane = threadIdx.x & 63;
    if (lane == 0) red[wv] = L2;
    __syncthreads();
    if (threadIdx.x == 0) {
        float blocksum = red[0] + red[1] + red[2] + red[3];
        atomicAdd(out, -REG_P * LN2 / (float)N * blocksum);
    }
    if (blockIdx.x == 0) {
        float ty2s = sum32(scalpart, lane);
        float sx2s = sum32(scalpart + 32, lane);
        float psis = sum32(scalpart + 64, lane);
        if (threadIdx.x == 0) {
            float scale = ty2s / (float)M;
            atomicAdd(out, (sx2s / (float)N) / scale
                         + psis / (float)M
                         + REG_P * logf((float)M));
        }
    }
}

extern "C" void kernel_launch(void* const* d_in, const int* in_sizes, int n_in,
                              void* d_out, int out_size, void* d_ws, size_t ws_size,
                              hipStream_t stream) {
    const float* src = (const float*)d_in[0];
    const float* tgt = (const float*)d_in[1];
    const float* psi = (const float*)d_in[2];
    const int D = 128;
    const int N = in_sizes[0] / D;   // 16384
    const int M = in_sizes[1] / D;   // 8192

    char* ws = (char*)d_ws;
    float* scalpart = (float*)ws;                                   // 3 x 32 floats
    float* sx2   = (float*)(ws + 512);
    float* ty2   = (float*)(ws + 512 + (size_t)N * 4);
    float* lpart = (float*)(ws + 512 + (size_t)N * 4 + (size_t)M * 4);
    size_t off = 512 + (size_t)N * 4 + (size_t)M * 4 + (size_t)N * NSPLIT * 4;
    off = (off + 255) & ~(size_t)255;
    unsigned short* Sb  = (unsigned short*)(ws + off);
    unsigned short* Tbs = Sb + (size_t)N * 128;

    k1_pack<<<(N + M) / 16, 256, 0, stream>>>(src, tgt, Sb, Tbs, sx2, ty2, N, M);
    k1b_sums<<<32, 256, 0, stream>>>(sx2, ty2, psi, scalpart, (float*)d_out, N, M);
    k3_main<<<(N / 128) * NSPLIT, 128, 0, stream>>>(Sb, Tbs, psi, ty2, scalpart, lpart, N, M);
    k4_reduce<<<N / 256, 256, 0, stream>>>(lpart, scalpart, (float*)d_out, N, M);
}

// Round 8
// 104.046 us; speedup vs baseline: 1.3396x; 1.0845x over previous
//
#include <hip/hip_runtime.h>
#include <stdint.h>

#define REG_P   0.05f
#define LOG2E   1.4426950408889634f
#define LN2     0.6931471805599453f
#define NSPLIT  8

typedef int   int32x8 __attribute__((ext_vector_type(8)));
typedef float floatx4 __attribute__((ext_vector_type(4)));

__device__ inline int32x8 load32B(const void* p) {
    union { int32x8 v; uint4 q[2]; } u;
    u.q[0] = ((const uint4*)p)[0];
    u.q[1] = ((const uint4*)p)[1];
    return u.v;
}

// sum of p[0..31]: butterfly masks 1..16 stay in each 32-lane half; every lane
// returns the exact 32-element sum (no scaling!).
__device__ inline float sum32(const float* __restrict__ p, int lane) {
    float v = p[lane & 31];
    #pragma unroll
    for (int mask = 1; mask < 32; mask <<= 1) v += __shfl_xor(v, mask, 64);
    return v;
}

// k1: pack fp32 -> fp8 e4m3 (hw cvt) + per-row fp32 squared norms.
// 256 thr = 16 rows x 16 chunks of 8 values (8 fp8 bytes per thread).
// S -> row-major Sb8 (128 B/row): A-fragment for 16x16x128 is row-major
//   contiguous (lane l16=row m, k = quad*32 + j -> bytes [quad*32, +32)).
// T -> fragment-ordered Tbs8: tile t (64 cols), chunk (ct,quad,l16) at
//   t*8192 + (ct*64 + quad*16 + l16)*32 holds T[t*64+ct*16+l16][quad*32..+31].
__global__ void k1_pack(const float* __restrict__ src, const float* __restrict__ tgt,
                        unsigned char* __restrict__ Sb8, unsigned char* __restrict__ Tbs8,
                        float* __restrict__ sx2, float* __restrict__ ty2,
                        int N, int M) {
    int tid = threadIdx.x;
    int r16 = tid >> 4;
    int c8  = tid & 15;
    int row_id = blockIdx.x * 16 + r16;
    bool isS = row_id < N;
    int row = isS ? row_id : row_id - N;
    const float4* sp = (const float4*)((isS ? src : tgt) + (size_t)row * 128 + c8 * 8);
    float4 f0 = sp[0], f1 = sp[1];
    int w0 = 0, w1 = 0;
    w0 = __builtin_amdgcn_cvt_pk_fp8_f32(f0.x, f0.y, w0, false);
    w0 = __builtin_amdgcn_cvt_pk_fp8_f32(f0.z, f0.w, w0, true);
    w1 = __builtin_amdgcn_cvt_pk_fp8_f32(f1.x, f1.y, w1, false);
    w1 = __builtin_amdgcn_cvt_pk_fp8_f32(f1.z, f1.w, w1, true);
    uint2 val = make_uint2((unsigned)w0, (unsigned)w1);
    float sq = f0.x*f0.x + f0.y*f0.y + f0.z*f0.z + f0.w*f0.w
             + f1.x*f1.x + f1.y*f1.y + f1.z*f1.z + f1.w*f1.w;
    #pragma unroll
    for (int mask = 1; mask < 16; mask <<= 1) sq += __shfl_xor(sq, mask, 16);
    if (isS) {
        ((uint2*)(Sb8 + (size_t)row * 128 + c8 * 8))[0] = val;
        if (c8 == 0) sx2[row] = sq;
    } else {
        int t = row >> 6, jc = row & 63;
        int ct = jc >> 4, l16 = jc & 15;
        int quad = c8 >> 2, rem = c8 & 3;
        size_t dst = (size_t)t * 8192 + (size_t)((ct * 64 + quad * 16 + l16) * 32 + rem * 8);
        ((uint2*)(Tbs8 + dst))[0] = val;
        if (c8 == 0) ty2[row] = sq;
    }
}

// k1b: 32 blocks, per-block partials to scalpart[3][32] (0: ty2, 1: sx2, 2: psi).
// Block 0 zero-inits d_out (k4 accumulates into it; stream order guarantees).
__global__ void k1b_sums(const float* __restrict__ sx2, const float* __restrict__ ty2,
                         const float* __restrict__ psi, float* __restrict__ scalpart,
                         float* __restrict__ out, int N, int M) {
    __shared__ float red[3][4];
    int tid = threadIdx.x;
    int gid = blockIdx.x * 256 + tid;
    float s_sx = 0.f, s_ty = 0.f, s_ps = 0.f;
    for (int i = gid; i < N; i += 32 * 256) s_sx += sx2[i];
    for (int j = gid; j < M; j += 32 * 256) { s_ty += ty2[j]; s_ps += psi[j]; }
    #pragma unroll
    for (int off = 32; off > 0; off >>= 1) {
        s_sx += __shfl_xor(s_sx, off, 64);
        s_ty += __shfl_xor(s_ty, off, 64);
        s_ps += __shfl_xor(s_ps, off, 64);
    }
    int wv = tid >> 6, lane = tid & 63;
    if (lane == 0) { red[0][wv] = s_ty; red[1][wv] = s_sx; red[2][wv] = s_ps; }
    __syncthreads();
    if (tid == 0) {
        scalpart[blockIdx.x]      = red[0][0] + red[0][1] + red[0][2] + red[0][3];
        scalpart[32 + blockIdx.x] = red[1][0] + red[1][1] + red[1][2] + red[1][3];
        scalpart[64 + blockIdx.x] = red[2][0] + red[2][1] + red[2][2] + red[2][3];
        if (blockIdx.x == 0) out[0] = 0.0f;
    }
}

// k3: l_i = sum_j exp2(b2_j + a2*dot_ij) with dot via MX-fp8 MFMA
// (mfma_scale_f32_16x16x128, K=128 in ONE instruction, scales = 1.0).
// No max shift: exponent in [-92,+33], fp32-safe.
// Block = 4 waves x 32 rows = 128 rows, one M-split (1024 cols = 16 tiles of 64).
// B fragments loaded GLOBAL->VGPR from fragment-ordered fp8 Tbs8 (32 B/lane
// contiguous), double-buffered by tile parity. ZERO barriers in the K loop;
// lagged epilogue software-pipelines exp2 against the next chunk's MFMA.
// split = b&7 -> per-XCD hot B-slice = 1 MB (L2-resident).
__global__ __launch_bounds__(256) void k3_main(
    const unsigned char* __restrict__ Sb8, const unsigned char* __restrict__ Tbs8,
    const float* __restrict__ psi, const float* __restrict__ ty2,
    const float* __restrict__ scalpart, float* __restrict__ lpart, int N, int M) {
    __shared__ float sb2a[1024];
    const int tid  = threadIdx.x;
    const int lane = tid & 63;
    const int wv   = tid >> 6;
    const int quad = lane >> 4, l16 = lane & 15;
    const int b = blockIdx.x;
    const int split = b & 7;
    const int i0 = (b >> 3) * 128;
    const int mspan = M / NSPLIT;            // 1024
    const int jstart = split * mspan;

    float ty2sum = sum32(scalpart, lane);
    float scale = ty2sum / (float)M;
    float c1 = 1.0f / (REG_P * scale);
    float a2 = 2.0f * LOG2E / (REG_P * scale);

    for (int idx = tid; idx < mspan; idx += 256) {
        int j = jstart + idx;
        sb2a[idx] = (psi[j] * (1.0f / REG_P) - ty2[j] * c1) * LOG2E;
    }
    __syncthreads();                          // the only barrier

    // A fragments: rows i0 + wv*32 + rt*16 + l16, k-bytes [quad*32, +32)
    int32x8 afrag[2];
    #pragma unroll
    for (int rt = 0; rt < 2; ++rt)
        afrag[rt] = load32B(Sb8 + (size_t)(i0 + wv * 32 + rt * 16 + l16) * 128 + quad * 32);

    float ls[2][4];
    #pragma unroll
    for (int rt = 0; rt < 2; ++rt)
        #pragma unroll
        for (int r = 0; r < 4; ++r) ls[rt][r] = 0.0f;

    const unsigned char* gb = Tbs8 + (size_t)jstart * 128 + (size_t)lane * 32;
    const floatx4 zero4 = (floatx4){0.f, 0.f, 0.f, 0.f};
    const int SC = 0x7F7F7F7F;               // E8M0 1.0 in every byte

    int32x8 bbuf[2][4];
    #pragma unroll
    for (int c = 0; c < 4; ++c) bbuf[0][c] = load32B(gb + c * 2048);

    floatx4 accP0, accP1;
    float bvP = 0.0f;
    bool first = true;

    #pragma unroll 2
    for (int tt = 0; tt < 16; ++tt) {
        const int p = tt & 1;
        if (tt < 15) {
            #pragma unroll
            for (int c = 0; c < 4; ++c)
                bbuf[p ^ 1][c] = load32B(gb + (size_t)((tt + 1) * 4 + c) * 2048);
        }
        #pragma unroll
        for (int c = 0; c < 4; ++c) {
            float bv = sb2a[(tt * 4 + c) * 16 + l16];
            floatx4 a0 = __builtin_amdgcn_mfma_scale_f32_16x16x128_f8f6f4(
                afrag[0], bbuf[p][c], zero4, 0, 0, 0, SC, 0, SC);
            floatx4 a1 = __builtin_amdgcn_mfma_scale_f32_16x16x128_f8f6f4(
                afrag[1], bbuf[p][c], zero4, 0, 0, 0, SC, 0, SC);
            if (!first) {                    // lagged epilogue: no MFMA-latency stall
                #pragma unroll
                for (int r = 0; r < 4; ++r) {
                    ls[0][r] += __builtin_amdgcn_exp2f(fmaf(a2, accP0[r], bvP));
                    ls[1][r] += __builtin_amdgcn_exp2f(fmaf(a2, accP1[r], bvP));
                }
            }
            accP0 = a0; accP1 = a1; bvP = bv;
            first = false;
        }
    }
    #pragma unroll
    for (int r = 0; r < 4; ++r) {
        ls[0][r] += __builtin_amdgcn_exp2f(fmaf(a2, accP0[r], bvP));
        ls[1][r] += __builtin_amdgcn_exp2f(fmaf(a2, accP1[r], bvP));
    }

    // sum over the 16 lanes (l16) sharing each row
    #pragma unroll
    for (int rt = 0; rt < 2; ++rt)
        #pragma unroll
        for (int r = 0; r < 4; ++r) {
            float v = ls[rt][r];
            #pragma unroll
            for (int mask = 1; mask < 16; mask <<= 1) v += __shfl_xor(v, mask, 64);
            if (l16 == 0) {
                int rowg = i0 + wv * 32 + rt * 16 + quad * 4 + r;
                lpart[(size_t)rowg * NSPLIT + split] = v;
            }
        }
}

// k4: one row per thread; L2_i = log2(sum of 8 partials); block partial ->
// atomicAdd of the scaled term into d_out. Block 0 adds the constant terms.
__global__ void k4_reduce(const float* __restrict__ lpart,
                          const float* __restrict__ scalpart,
                          float* __restrict__ out, int N, int M) {
    __shared__ float red[4];
    int i = blockIdx.x * 256 + threadIdx.x;
    const float4* lp = (const float4*)(lpart + (size_t)i * NSPLIT);
    float4 p0 = lp[0], p1 = lp[1];
    float s = (p0.x + p0.y + p0.z + p0.w) + (p1.x + p1.y + p1.z + p1.w);
    float L2 = __builtin_amdgcn_logf(s);     // v_log_f32 = log2
    #pragma unroll
    for (int off = 32; off > 0; off >>= 1) L2 += __shfl_xor(L2, off, 64);
    int wv = threadIdx.x >> 6, lane = threadIdx.x & 63;
    if (lane == 0) red[wv] = L2;
    __syncthreads();
    if (threadIdx.x == 0) {
        float blocksum = red[0] + red[1] + red[2] + red[3];
        atomicAdd(out, -REG_P * LN2 / (float)N * blocksum);
    }
    if (blockIdx.x == 0) {
        float ty2s = sum32(scalpart, lane);
        float sx2s = sum32(scalpart + 32, lane);
        float psis = sum32(scalpart + 64, lane);
        if (threadIdx.x == 0) {
            float scale = ty2s / (float)M;
            atomicAdd(out, (sx2s / (float)N) / scale
                         + psis / (float)M
                         + REG_P * logf((float)M));
        }
    }
}

extern "C" void kernel_launch(void* const* d_in, const int* in_sizes, int n_in,
                              void* d_out, int out_size, void* d_ws, size_t ws_size,
                              hipStream_t stream) {
    const float* src = (const float*)d_in[0];
    const float* tgt = (const float*)d_in[1];
    const float* psi = (const float*)d_in[2];
    const int D = 128;
    const int N = in_sizes[0] / D;   // 16384
    const int M = in_sizes[1] / D;   // 8192

    char* ws = (char*)d_ws;
    float* scalpart = (float*)ws;                                   // 3 x 32 floats
    float* sx2   = (float*)(ws + 512);
    float* ty2   = (float*)(ws + 512 + (size_t)N * 4);
    float* lpart = (float*)(ws + 512 + (size_t)N * 4 + (size_t)M * 4);
    size_t off = 512 + (size_t)N * 4 + (size_t)M * 4 + (size_t)N * NSPLIT * 4;
    off = (off + 255) & ~(size_t)255;
    unsigned char* Sb8  = (unsigned char*)(ws + off);
    unsigned char* Tbs8 = Sb8 + (size_t)N * 128;

    k1_pack<<<(N + M) / 16, 256, 0, stream>>>(src, tgt, Sb8, Tbs8, sx2, ty2, N, M);
    k1b_sums<<<32, 256, 0, stream>>>(sx2, ty2, psi, scalpart, (float*)d_out, N, M);
    k3_main<<<(N / 128) * NSPLIT, 256, 0, stream>>>(Sb8, Tbs8, psi, ty2, scalpart, lpart, N, M);
    k4_reduce<<<N / 256, 256, 0, stream>>>(lpart, scalpart, (float*)d_out, N, M);
}

// Round 9
// 100.208 us; speedup vs baseline: 1.3909x; 1.0383x over previous
//
#include <hip/hip_runtime.h>
#include <stdint.h>

#define REG_P   0.05f
#define LOG2E   1.4426950408889634f
#define LN2     0.6931471805599453f
#define NSPLIT  8

typedef int   int32x8 __attribute__((ext_vector_type(8)));
typedef float floatx4 __attribute__((ext_vector_type(4)));

__device__ inline int32x8 load32B(const void* p) {
    union { int32x8 v; uint4 q[2]; } u;
    u.q[0] = ((const uint4*)p)[0];
    u.q[1] = ((const uint4*)p)[1];
    return u.v;
}

// block-wide sum of ty2[0..M): float4 grid-stride + wave butterfly + LDS.
// All 256 threads return the exact total. Uses redbuf[4]; leaves after one barrier.
__device__ inline float block_sum_f(const float* __restrict__ v, int M, int tid,
                                    float* redbuf) {
    float s = 0.f;
    const float4* v4 = (const float4*)v;
    for (int j = tid; j < (M >> 2); j += 256) {
        float4 q = v4[j];
        s += (q.x + q.y) + (q.z + q.w);
    }
    #pragma unroll
    for (int mask = 1; mask < 64; mask <<= 1) s += __shfl_xor(s, mask, 64);
    int wv = tid >> 6, lane = tid & 63;
    if (lane == 0) redbuf[wv] = s;
    __syncthreads();
    return (redbuf[0] + redbuf[1]) + (redbuf[2] + redbuf[3]);
}

// k1: pack fp32 -> fp8 e4m3 (hw cvt) + per-row fp32 squared norms.
// 256 thr = 16 rows x 16 chunks of 8 values. S -> row-major Sb8 (128 B/row).
// T -> fragment-ordered Tbs8: tile t (64 cols), chunk (ct,quad,l16) at
//   t*8192 + (ct*64 + quad*16 + l16)*32 holds T[t*64+ct*16+l16][quad*32..+31].
// Block 0 zero-inits d_out (k4 accumulates into it; stream order guarantees).
__global__ void k1_pack(const float* __restrict__ src, const float* __restrict__ tgt,
                        unsigned char* __restrict__ Sb8, unsigned char* __restrict__ Tbs8,
                        float* __restrict__ sx2, float* __restrict__ ty2,
                        float* __restrict__ out, int N, int M) {
    int tid = threadIdx.x;
    if (blockIdx.x == 0 && tid == 0) out[0] = 0.0f;
    int r16 = tid >> 4;
    int c8  = tid & 15;
    int row_id = blockIdx.x * 16 + r16;
    bool isS = row_id < N;
    int row = isS ? row_id : row_id - N;
    const float4* sp = (const float4*)((isS ? src : tgt) + (size_t)row * 128 + c8 * 8);
    float4 f0 = sp[0], f1 = sp[1];
    int w0 = 0, w1 = 0;
    w0 = __builtin_amdgcn_cvt_pk_fp8_f32(f0.x, f0.y, w0, false);
    w0 = __builtin_amdgcn_cvt_pk_fp8_f32(f0.z, f0.w, w0, true);
    w1 = __builtin_amdgcn_cvt_pk_fp8_f32(f1.x, f1.y, w1, false);
    w1 = __builtin_amdgcn_cvt_pk_fp8_f32(f1.z, f1.w, w1, true);
    uint2 val = make_uint2((unsigned)w0, (unsigned)w1);
    float sq = f0.x*f0.x + f0.y*f0.y + f0.z*f0.z + f0.w*f0.w
             + f1.x*f1.x + f1.y*f1.y + f1.z*f1.z + f1.w*f1.w;
    #pragma unroll
    for (int mask = 1; mask < 16; mask <<= 1) sq += __shfl_xor(sq, mask, 16);
    if (isS) {
        ((uint2*)(Sb8 + (size_t)row * 128 + c8 * 8))[0] = val;
        if (c8 == 0) sx2[row] = sq;
    } else {
        int t = row >> 6, jc = row & 63;
        int ct = jc >> 4, l16 = jc & 15;
        int quad = c8 >> 2, rem = c8 & 3;
        size_t dst = (size_t)t * 8192 + (size_t)((ct * 64 + quad * 16 + l16) * 32 + rem * 8);
        ((uint2*)(Tbs8 + dst))[0] = val;
        if (c8 == 0) ty2[row] = sq;
    }
}

// k3: l_i = sum_j exp2(b2_j + a2*dot_ij) via MX-fp8 MFMA (16x16x128, K=128 in
// one instruction, scales = 1.0 / 0x7F). No max shift: exponent in [-92,+33].
// Block = 4 waves x 64 rows = 256 rows, one M-split (1024 cols = 16 tiles).
// Each wave reads split-B ONCE for 64 rows (halves L2 traffic vs 32-row waves):
// per-XCD B traffic ~32 MB. Barrier-free K loop, global->VGPR double-buffered
// B loads, lagged exp2 epilogue. ty2-sum self-computed (no k1b kernel).
// split = b&7 -> per-XCD hot B-slice = 128 KB (L2-resident).
__global__ __launch_bounds__(256, 2) void k3_main(
    const unsigned char* __restrict__ Sb8, const unsigned char* __restrict__ Tbs8,
    const float* __restrict__ psi, const float* __restrict__ ty2,
    float* __restrict__ lpart, int N, int M) {
    __shared__ float sb2a[1024];
    __shared__ float redA[4];
    const int tid  = threadIdx.x;
    const int lane = tid & 63;
    const int wv   = tid >> 6;
    const int quad = lane >> 4, l16 = lane & 15;
    const int b = blockIdx.x;
    const int split = b & 7;
    const int i0 = (b >> 3) * 256;
    const int mspan = M / NSPLIT;            // 1024
    const int jstart = split * mspan;

    float ty2sum = block_sum_f(ty2, M, tid, redA);   // includes one barrier
    float scale = ty2sum / (float)M;
    float c1 = 1.0f / (REG_P * scale);
    float a2 = 2.0f * LOG2E / (REG_P * scale);

    for (int idx = tid; idx < mspan; idx += 256) {
        int j = jstart + idx;
        sb2a[idx] = (psi[j] * (1.0f / REG_P) - ty2[j] * c1) * LOG2E;
    }
    __syncthreads();                          // last barrier

    // A fragments: rows i0 + wv*64 + rt*16 + l16, k-bytes [quad*32, +32)
    int32x8 afrag[4];
    #pragma unroll
    for (int rt = 0; rt < 4; ++rt)
        afrag[rt] = load32B(Sb8 + (size_t)(i0 + wv * 64 + rt * 16 + l16) * 128 + quad * 32);

    float ls[4][4];
    #pragma unroll
    for (int rt = 0; rt < 4; ++rt)
        #pragma unroll
        for (int r = 0; r < 4; ++r) ls[rt][r] = 0.0f;

    const unsigned char* gb = Tbs8 + (size_t)jstart * 128 + (size_t)lane * 32;
    const floatx4 zero4 = (floatx4){0.f, 0.f, 0.f, 0.f};
    const int SC = 0x7F7F7F7F;               // E8M0 1.0 in every byte

    int32x8 bbuf[2][4];
    #pragma unroll
    for (int c = 0; c < 4; ++c) bbuf[0][c] = load32B(gb + c * 2048);

    floatx4 accP[4];
    float bvP = 0.0f;
    bool first = true;

    #pragma unroll 2
    for (int tt = 0; tt < 16; ++tt) {
        const int p = tt & 1;
        if (tt < 15) {
            #pragma unroll
            for (int c = 0; c < 4; ++c)
                bbuf[p ^ 1][c] = load32B(gb + (size_t)((tt + 1) * 4 + c) * 2048);
        }
        #pragma unroll
        for (int c = 0; c < 4; ++c) {
            float bv = sb2a[(tt * 4 + c) * 16 + l16];
            floatx4 a[4];
            #pragma unroll
            for (int rt = 0; rt < 4; ++rt)
                a[rt] = __builtin_amdgcn_mfma_scale_f32_16x16x128_f8f6f4(
                    afrag[rt], bbuf[p][c], zero4, 0, 0, 0, SC, 0, SC);
            if (!first) {                    // lagged epilogue: no MFMA-latency stall
                #pragma unroll
                for (int rt = 0; rt < 4; ++rt)
                    #pragma unroll
                    for (int r = 0; r < 4; ++r)
                        ls[rt][r] += __builtin_amdgcn_exp2f(fmaf(a2, accP[rt][r], bvP));
            }
            #pragma unroll
            for (int rt = 0; rt < 4; ++rt) accP[rt] = a[rt];
            bvP = bv;
            first = false;
        }
    }
    #pragma unroll
    for (int rt = 0; rt < 4; ++rt)
        #pragma unroll
        for (int r = 0; r < 4; ++r)
            ls[rt][r] += __builtin_amdgcn_exp2f(fmaf(a2, accP[rt][r], bvP));

    // sum over the 16 lanes (l16) sharing each row
    #pragma unroll
    for (int rt = 0; rt < 4; ++rt)
        #pragma unroll
        for (int r = 0; r < 4; ++r) {
            float v = ls[rt][r];
            #pragma unroll
            for (int mask = 1; mask < 16; mask <<= 1) v += __shfl_xor(v, mask, 64);
            if (l16 == 0) {
                int rowg = i0 + wv * 64 + rt * 16 + quad * 4 + r;
                lpart[(size_t)rowg * NSPLIT + split] = v;
            }
        }
}

// k4: one row per thread. Self-computes ty2sum (scale). Per-row term:
//   (-REG*LN2*log2(sum_p lpart) + sx2[i]/scale) / N, plus psi[i]/M for i<M.
// Block reduce -> one atomicAdd into d_out. Block 0 adds REG*ln(M).
__global__ void k4_reduce(const float* __restrict__ lpart,
                          const float* __restrict__ sx2,
                          const float* __restrict__ psi,
                          const float* __restrict__ ty2,
                          float* __restrict__ out, int N, int M) {
    __shared__ float redA[4];
    __shared__ float redB[4];
    int tid = threadIdx.x;
    float ty2s = block_sum_f(ty2, M, tid, redA);
    float scale = ty2s / (float)M;

    int i = blockIdx.x * 256 + tid;
    const float4* lp = (const float4*)(lpart + (size_t)i * NSPLIT);
    float4 p0 = lp[0], p1 = lp[1];
    float s = (p0.x + p0.y + p0.z + p0.w) + (p1.x + p1.y + p1.z + p1.w);
    float L2 = __builtin_amdgcn_logf(s);     // v_log_f32 = log2
    float t = (-REG_P * LN2 * L2 + sx2[i] / scale) * (1.0f / (float)N);
    if (i < M) t += psi[i] * (1.0f / (float)M);
    #pragma unroll
    for (int mask = 1; mask < 64; mask <<= 1) t += __shfl_xor(t, mask, 64);
    int wv = tid >> 6, lane = tid & 63;
    if (lane == 0) redB[wv] = t;
    __syncthreads();
    if (tid == 0) {
        float total = (redB[0] + redB[1]) + (redB[2] + redB[3]);
        if (blockIdx.x == 0) total += REG_P * logf((float)M);
        atomicAdd(out, total);
    }
}

extern "C" void kernel_launch(void* const* d_in, const int* in_sizes, int n_in,
                              void* d_out, int out_size, void* d_ws, size_t ws_size,
                              hipStream_t stream) {
    const float* src = (const float*)d_in[0];
    const float* tgt = (const float*)d_in[1];
    const float* psi = (const float*)d_in[2];
    const int D = 128;
    const int N = in_sizes[0] / D;   // 16384
    const int M = in_sizes[1] / D;   // 8192

    char* ws = (char*)d_ws;
    float* sx2   = (float*)ws;
    float* ty2   = (float*)(ws + (size_t)N * 4);
    float* lpart = (float*)(ws + (size_t)N * 4 + (size_t)M * 4);
    size_t off = (size_t)N * 4 + (size_t)M * 4 + (size_t)N * NSPLIT * 4;
    off = (off + 255) & ~(size_t)255;
    unsigned char* Sb8  = (unsigned char*)(ws + off);
    unsigned char* Tbs8 = Sb8 + (size_t)N * 128;

    k1_pack<<<(N + M) / 16, 256, 0, stream>>>(src, tgt, Sb8, Tbs8, sx2, ty2,
                                              (float*)d_out, N, M);
    k3_main<<<(N / 256) * NSPLIT, 256, 0, stream>>>(Sb8, Tbs8, psi, ty2, lpart, N, M);
    k4_reduce<<<N / 256, 256, 0, stream>>>(lpart, sx2, psi, ty2, (float*)d_out, N, M);
}

// Round 10
// 96.327 us; speedup vs baseline: 1.4470x; 1.0403x over previous
//
#include <hip/hip_runtime.h>
#include <stdint.h>

#define REG_P   0.05f
#define LOG2E   1.4426950408889634f
#define LN2     0.6931471805599453f
#define NSPLIT  8

typedef int   int32x8 __attribute__((ext_vector_type(8)));
typedef float floatx4 __attribute__((ext_vector_type(4)));

__device__ inline int32x8 load32B(const void* p) {
    union { int32x8 v; uint4 q[2]; } u;
    u.q[0] = ((const uint4*)p)[0];
    u.q[1] = ((const uint4*)p)[1];
    return u.v;
}

// block-wide sum of v[0..M): float4 grid-stride + wave butterfly + LDS.
// All 256 threads return the exact total. Uses redbuf[4]; one internal barrier.
__device__ inline float block_sum_f(const float* __restrict__ v, int M, int tid,
                                    float* redbuf) {
    float s = 0.f;
    const float4* v4 = (const float4*)v;
    for (int j = tid; j < (M >> 2); j += 256) {
        float4 q = v4[j];
        s += (q.x + q.y) + (q.z + q.w);
    }
    #pragma unroll
    for (int mask = 1; mask < 64; mask <<= 1) s += __shfl_xor(s, mask, 64);
    int wv = tid >> 6, lane = tid & 63;
    if (lane == 0) redbuf[wv] = s;
    __syncthreads();
    return (redbuf[0] + redbuf[1]) + (redbuf[2] + redbuf[3]);
}

// k1: pack fp32 -> fp8 e4m3 (hw cvt) + per-row fp32 squared norms.
// 256 thr = 16 rows x 16 chunks of 8 values. S -> row-major Sb8 (128 B/row).
// T -> fragment-ordered Tbs8: tile t (64 cols), chunk (ct,quad,l16) at
//   t*8192 + (ct*64 + quad*16 + l16)*32 holds T[t*64+ct*16+l16][quad*32..+31].
// Block 0 zero-inits d_out (k4 accumulates into it; stream order guarantees).
__global__ void k1_pack(const float* __restrict__ src, const float* __restrict__ tgt,
                        unsigned char* __restrict__ Sb8, unsigned char* __restrict__ Tbs8,
                        float* __restrict__ sx2, float* __restrict__ ty2,
                        float* __restrict__ out, int N, int M) {
    int tid = threadIdx.x;
    if (blockIdx.x == 0 && tid == 0) out[0] = 0.0f;
    int r16 = tid >> 4;
    int c8  = tid & 15;
    int row_id = blockIdx.x * 16 + r16;
    bool isS = row_id < N;
    int row = isS ? row_id : row_id - N;
    const float4* sp = (const float4*)((isS ? src : tgt) + (size_t)row * 128 + c8 * 8);
    float4 f0 = sp[0], f1 = sp[1];
    int w0 = 0, w1 = 0;
    w0 = __builtin_amdgcn_cvt_pk_fp8_f32(f0.x, f0.y, w0, false);
    w0 = __builtin_amdgcn_cvt_pk_fp8_f32(f0.z, f0.w, w0, true);
    w1 = __builtin_amdgcn_cvt_pk_fp8_f32(f1.x, f1.y, w1, false);
    w1 = __builtin_amdgcn_cvt_pk_fp8_f32(f1.z, f1.w, w1, true);
    uint2 val = make_uint2((unsigned)w0, (unsigned)w1);
    float sq = f0.x*f0.x + f0.y*f0.y + f0.z*f0.z + f0.w*f0.w
             + f1.x*f1.x + f1.y*f1.y + f1.z*f1.z + f1.w*f1.w;
    #pragma unroll
    for (int mask = 1; mask < 16; mask <<= 1) sq += __shfl_xor(sq, mask, 16);
    if (isS) {
        ((uint2*)(Sb8 + (size_t)row * 128 + c8 * 8))[0] = val;
        if (c8 == 0) sx2[row] = sq;
    } else {
        int t = row >> 6, jc = row & 63;
        int ct = jc >> 4, l16 = jc & 15;
        int quad = c8 >> 2, rem = c8 & 3;
        size_t dst = (size_t)t * 8192 + (size_t)((ct * 64 + quad * 16 + l16) * 32 + rem * 8);
        ((uint2*)(Tbs8 + dst))[0] = val;
        if (c8 == 0) ty2[row] = sq;
    }
}

// k3: l_i = sum_j exp2(b2_j + a2*dot_ij) via MX-fp8 MFMA (16x16x128, scales=1.0).
// No max shift: exponent in [-92,+33], fp32-safe.
// Block = 4 waves x 32 rows = 128 rows, one M-split (1024 cols = 64 chunks of 16).
// Grid 1024 = 4 blocks/CU = 4 waves/SIMD (launch_bounds(256,4), ~95 VGPRs):
// TLP covers MFMA->exp2 and load latency — R9's 2-waves/SIMD was stall-bound.
// B: chunk-level rotation prefetch (distance 2), barrier-free K loop; prefetch
// reads up to 4KB past the split (inside ws slack, never consumed).
// Lag-1 epilogue: exp2 of chunk u-1 issues after MFMAs of chunk u.
// split = b&7 -> per-XCD hot B-slice = 128 KB (L2-resident).
__global__ __launch_bounds__(256, 4) void k3_main(
    const unsigned char* __restrict__ Sb8, const unsigned char* __restrict__ Tbs8,
    const float* __restrict__ psi, const float* __restrict__ ty2,
    float* __restrict__ lpart, int N, int M) {
    __shared__ float sb2a[1024];
    __shared__ float redA[4];
    const int tid  = threadIdx.x;
    const int lane = tid & 63;
    const int wv   = tid >> 6;
    const int quad = lane >> 4, l16 = lane & 15;
    const int b = blockIdx.x;
    const int split = b & 7;
    const int i0 = (b >> 3) * 128;
    const int mspan = M / NSPLIT;            // 1024
    const int jstart = split * mspan;

    float ty2sum = block_sum_f(ty2, M, tid, redA);   // includes one barrier
    float scale = ty2sum / (float)M;
    float c1 = 1.0f / (REG_P * scale);
    float a2 = 2.0f * LOG2E / (REG_P * scale);

    for (int idx = tid; idx < mspan; idx += 256) {
        int j = jstart + idx;
        sb2a[idx] = (psi[j] * (1.0f / REG_P) - ty2[j] * c1) * LOG2E;
    }
    __syncthreads();                          // last barrier

    // A fragments: rows i0 + wv*32 + rt*16 + l16, k-bytes [quad*32, +32)
    int32x8 afrag[2];
    #pragma unroll
    for (int rt = 0; rt < 2; ++rt)
        afrag[rt] = load32B(Sb8 + (size_t)(i0 + wv * 32 + rt * 16 + l16) * 128 + quad * 32);

    float ls[2][4];
    #pragma unroll
    for (int rt = 0; rt < 2; ++rt)
        #pragma unroll
        for (int r = 0; r < 4; ++r) ls[rt][r] = 0.0f;

    const unsigned char* gb = Tbs8 + (size_t)jstart * 128 + (size_t)lane * 32;
    const floatx4 zero4 = (floatx4){0.f, 0.f, 0.f, 0.f};
    const int SC = 0x7F7F7F7F;               // E8M0 1.0 in every byte

    int32x8 bc = load32B(gb);                // chunk 0
    int32x8 bn = load32B(gb + 2048);         // chunk 1
    floatx4 pA, pB;                          // lag-1 accumulators
    float bvP = 0.0f;

    #pragma unroll 4
    for (int u = 0; u < 64; ++u) {
        float bv = sb2a[u * 16 + l16];
        floatx4 c0 = __builtin_amdgcn_mfma_scale_f32_16x16x128_f8f6f4(
            afrag[0], bc, zero4, 0, 0, 0, SC, 0, SC);
        floatx4 c1v = __builtin_amdgcn_mfma_scale_f32_16x16x128_f8f6f4(
            afrag[1], bc, zero4, 0, 0, 0, SC, 0, SC);
        int32x8 bf = load32B(gb + (size_t)(u + 2) * 2048);  // <=4KB OOB, never used
        if (u) {
            #pragma unroll
            for (int r = 0; r < 4; ++r) {
                ls[0][r] += __builtin_amdgcn_exp2f(fmaf(a2, pA[r], bvP));
                ls[1][r] += __builtin_amdgcn_exp2f(fmaf(a2, pB[r], bvP));
            }
        }
        pA = c0; pB = c1v; bvP = bv;
        bc = bn; bn = bf;
    }
    #pragma unroll
    for (int r = 0; r < 4; ++r) {
        ls[0][r] += __builtin_amdgcn_exp2f(fmaf(a2, pA[r], bvP));
        ls[1][r] += __builtin_amdgcn_exp2f(fmaf(a2, pB[r], bvP));
    }

    // sum over the 16 lanes (l16) sharing each row
    #pragma unroll
    for (int rt = 0; rt < 2; ++rt)
        #pragma unroll
        for (int r = 0; r < 4; ++r) {
            float v = ls[rt][r];
            #pragma unroll
            for (int mask = 1; mask < 16; mask <<= 1) v += __shfl_xor(v, mask, 64);
            if (l16 == 0) {
                int rowg = i0 + wv * 32 + rt * 16 + quad * 4 + r;
                lpart[(size_t)rowg * NSPLIT + split] = v;
            }
        }
}

// k4: one row per thread. Self-computes ty2sum (scale). Per-row term:
//   (-REG*LN2*log2(sum_p lpart) + sx2[i]/scale) / N, plus psi[i]/M for i<M.
// Block reduce -> one atomicAdd into d_out. Block 0 adds REG*ln(M).
__global__ void k4_reduce(const float* __restrict__ lpart,
                          const float* __restrict__ sx2,
                          const float* __restrict__ psi,
                          const float* __restrict__ ty2,
                          float* __restrict__ out, int N, int M) {
    __shared__ float redA[4];
    __shared__ float redB[4];
    int tid = threadIdx.x;
    float ty2s = block_sum_f(ty2, M, tid, redA);
    float scale = ty2s / (float)M;

    int i = blockIdx.x * 256 + tid;
    const float4* lp = (const float4*)(lpart + (size_t)i * NSPLIT);
    float4 p0 = lp[0], p1 = lp[1];
    float s = (p0.x + p0.y + p0.z + p0.w) + (p1.x + p1.y + p1.z + p1.w);
    float L2 = __builtin_amdgcn_logf(s);     // v_log_f32 = log2
    float t = (-REG_P * LN2 * L2 + sx2[i] / scale) * (1.0f / (float)N);
    if (i < M) t += psi[i] * (1.0f / (float)M);
    #pragma unroll
    for (int mask = 1; mask < 64; mask <<= 1) t += __shfl_xor(t, mask, 64);
    int wv = tid >> 6, lane = tid & 63;
    if (lane == 0) redB[wv] = t;
    __syncthreads();
    if (tid == 0) {
        float total = (redB[0] + redB[1]) + (redB[2] + redB[3]);
        if (blockIdx.x == 0) total += REG_P * logf((float)M);
        atomicAdd(out, total);
    }
}

extern "C" void kernel_launch(void* const* d_in, const int* in_sizes, int n_in,
                              void* d_out, int out_size, void* d_ws, size_t ws_size,
                              hipStream_t stream) {
    const float* src = (const float*)d_in[0];
    const float* tgt = (const float*)d_in[1];
    const float* psi = (const float*)d_in[2];
    const int D = 128;
    const int N = in_sizes[0] / D;   // 16384
    const int M = in_sizes[1] / D;   // 8192

    char* ws = (char*)d_ws;
    float* sx2   = (float*)ws;
    float* ty2   = (float*)(ws + (size_t)N * 4);
    float* lpart = (float*)(ws + (size_t)N * 4 + (size_t)M * 4);
    size_t off = (size_t)N * 4 + (size_t)M * 4 + (size_t)N * NSPLIT * 4;
    off = (off + 255) & ~(size_t)255;
    unsigned char* Sb8  = (unsigned char*)(ws + off);
    unsigned char* Tbs8 = Sb8 + (size_t)N * 128;   // 1 MB Tbs8 + >4KB slack after

    k1_pack<<<(N + M) / 16, 256, 0, stream>>>(src, tgt, Sb8, Tbs8, sx2, ty2,
                                              (float*)d_out, N, M);
    k3_main<<<(N / 128) * NSPLIT, 256, 0, stream>>>(Sb8, Tbs8, psi, ty2, lpart, N, M);
    k4_reduce<<<N / 256, 256, 0, stream>>>(lpart, sx2, psi, ty2, (float*)d_out, N, M);
}